// Round 1
// 360.470 us; speedup vs baseline: 1.1939x; 1.1939x over previous
//
#include <hip/hip_runtime.h>

#define B_   2
#define S_   2048
#define H_   32
#define D_   64
#define HID_ 2048

typedef unsigned short ushort_t;
typedef __attribute__((ext_vector_type(8))) short short8;
typedef __attribute__((ext_vector_type(4))) float floatx4;

typedef const __attribute__((address_space(1))) char* gas_ptr;
typedef __attribute__((address_space(3))) char* las_ptr;

__device__ __forceinline__ float bf2f(ushort_t u) {
    union { unsigned int i; float f; } v; v.i = ((unsigned int)u) << 16; return v.f;
}
__device__ __forceinline__ ushort_t f2bf(float f) {
    union { float f; unsigned int i; } v; v.f = f;
    unsigned int x = v.i;
    unsigned int r = x + 0x7fffu + ((x >> 16) & 1u);
    return (ushort_t)(r >> 16);
}

// exp2 via hardware v_exp_f32 (no log2e multiply).
__device__ __forceinline__ float fexp2(float x) {
#if __has_builtin(__builtin_amdgcn_exp2f)
    return __builtin_amdgcn_exp2f(x);
#else
    float r; asm("v_exp_f32 %0, %1" : "=v"(r) : "v"(x)); return r;
#endif
}

// Packed f32->bf16 RNE convert: dst = {lo16: cvt(a), hi16: cvt(b)}.
__device__ __forceinline__ unsigned cvt_pk_bf16(float a, float b) {
    unsigned r;
    asm("v_cvt_pk_bf16_f32 %0, %1, %2" : "=v"(r) : "v"(a), "v"(b));
    return r;
}

// fp32 -> bf16 cast, 8 elements/thread.
__global__ __launch_bounds__(256) void cast_f32_bf16(const float* __restrict__ in,
                                                     ushort_t* __restrict__ out,
                                                     int n8) {
    int i = blockIdx.x * 256 + threadIdx.x;
    if (i >= n8) return;
    const float4* p = (const float4*)(in + (size_t)i * 8);
    float4 a = p[0], b = p[1];
    uint4 o;
    o.x = cvt_pk_bf16(a.x, a.y);
    o.y = cvt_pk_bf16(a.z, a.w);
    o.z = cvt_pk_bf16(b.x, b.y);
    o.w = cvt_pk_bf16(b.z, b.w);
    *(uint4*)(out + (size_t)i * 8) = o;
}

// Pack int32 bool mask -> bitmask, 1 bit per element.
__global__ __launch_bounds__(256) void mask_pack(const int* __restrict__ m,
                                                 unsigned long long* __restrict__ bits) {
    int idx = blockIdx.x * 256 + threadIdx.x;
    unsigned long long bal = __ballot(m[idx] != 0);
    if ((threadIdx.x & 63) == 0) bits[idx >> 6] = bal;
}

// C = A @ B^T.  (m97-style; unchanged.)
template <bool OF32>
__global__ __launch_bounds__(256) void gemm_bt(const ushort_t* __restrict__ A,
                                               const ushort_t* __restrict__ Bm,
                                               void* __restrict__ Cv,
                                               int M, int N, int K) {
    __shared__ ushort_t lA[128 * 32];
    __shared__ ushort_t lB[128 * 32];
    const int tid  = threadIdx.x;
    const int lane = tid & 63, wave = tid >> 6;
    const int quad = lane >> 4, l16 = lane & 15;
    const int wm = wave >> 1, wn = wave & 1;
    const int m0 = blockIdx.y * 128, n0 = blockIdx.x * 128;

    const int srow = tid >> 2;
    const int gseg = (tid & 3) ^ ((tid >> 3) & 3);
    const ushort_t* gA = A + (size_t)(m0 + srow) * K + gseg * 8;
    const ushort_t* gB = Bm + (size_t)(n0 + srow) * K + gseg * 8;

    const int fseg = quad ^ ((l16 >> 1) & 3);

    floatx4 acc[4][4];
#pragma unroll
    for (int i = 0; i < 4; i++)
#pragma unroll
        for (int j = 0; j < 4; j++) acc[i][j] = (floatx4){0.f, 0.f, 0.f, 0.f};

    for (int k0 = 0; k0 < K; k0 += 32) {
#pragma unroll
        for (int j = 0; j < 2; j++) {
            __builtin_amdgcn_global_load_lds(
                (gas_ptr)(gA + (size_t)j * 64 * K + k0),
                (las_ptr)(lA + j * 2048 + wave * 512), 16, 0, 0);
            __builtin_amdgcn_global_load_lds(
                (gas_ptr)(gB + (size_t)j * 64 * K + k0),
                (las_ptr)(lB + j * 2048 + wave * 512), 16, 0, 0);
        }
        __syncthreads();

        short8 aF[4], bF[4];
#pragma unroll
        for (int mi = 0; mi < 4; mi++)
            aF[mi] = *(const short8*)&lA[(wm * 64 + mi * 16 + l16) * 32 + fseg * 8];
#pragma unroll
        for (int ni = 0; ni < 4; ni++)
            bF[ni] = *(const short8*)&lB[(wn * 64 + ni * 16 + l16) * 32 + fseg * 8];
#pragma unroll
        for (int mi = 0; mi < 4; mi++)
#pragma unroll
            for (int ni = 0; ni < 4; ni++)
                acc[mi][ni] = __builtin_amdgcn_mfma_f32_16x16x32_bf16(aF[mi], bF[ni], acc[mi][ni], 0, 0, 0);
        __syncthreads();
    }

#pragma unroll
    for (int mi = 0; mi < 4; mi++)
#pragma unroll
        for (int ni = 0; ni < 4; ni++)
#pragma unroll
            for (int r = 0; r < 4; r++) {
                int row = m0 + wm * 64 + mi * 16 + quad * 4 + r;
                int col = n0 + wn * 64 + ni * 16 + l16;
                if (OF32) ((float*)Cv)[(size_t)row * N + col] = acc[mi][ni][r];
                else      ((ushort_t*)Cv)[(size_t)row * N + col] = f2bf(acc[mi][ni][r]);
            }
}

// qkv: (B,S,H,3D) bf16 -> q_rot (pre-scaled by log2e/8), k_rot as (B,H,S,D) bf16.
__global__ __launch_bounds__(256) void rope_qk(const ushort_t* __restrict__ qkv,
                                               const int* __restrict__ pos,
                                               ushort_t* __restrict__ qr,
                                               ushort_t* __restrict__ kr) {
    int idx = blockIdx.x * 256 + threadIdx.x;   // (b,h,s,d): d fastest
    int d = idx & 63;
    int s = (idx >> 6) & 2047;
    int h = (idx >> 17) & 31;
    int b = idx >> 22;
    size_t qbase = ((size_t)(b * S_ + s)) * (3 * H_ * D_) + h * (3 * D_);
    int i  = d & 31;
    int d2 = d ^ 32;
    float x   = bf2f(qkv[qbase + d]);
    float xp  = bf2f(qkv[qbase + d2]);
    float kx  = bf2f(qkv[qbase + 64 + d]);
    float kxp = bf2f(qkv[qbase + 64 + d2]);
    int   p   = pos[b * S_ + s];
    // inv = 10000^(-2i/64) = exp2(-i * log2(10000)/32)
    float inv = fexp2((float)i * -0.41524101186092985f);
    float t   = (float)p * inv;
    float c = cosf(t), sn = sinf(t);
    float rq = (d < 32) ? -xp : xp;
    float rk = (d < 32) ? -kxp : kxp;
    // q pre-scale: (1/sqrt(64)) * log2(e) so attn can use raw exp2
    float qo = (x * c + rq * sn) * 0.18033688011112042f;
    float ko = kx * c + rk * sn;
    size_t o = ((size_t)(b * H_ + h) * S_ + s) * D_ + d;
    qr[o] = f2bf(qo);
    kr[o] = f2bf(ko);
}

// v transpose: qkv (B,S,H,3D) -> vt (B,H,D,S), LDS-tiled 64x64 (coalesced both sides).
__global__ __launch_bounds__(256) void v_trans(const ushort_t* __restrict__ qkv,
                                               ushort_t* __restrict__ vt) {
    __shared__ ushort_t tile[64][72];           // +8 pad
    const int bid = blockIdx.x;                 // grid = B*H * (S/64) = 2048
    const int g  = bid >> 5;                    // head-instance (b*H+h)
    const int s0 = (bid & 31) * 64;
    const int b = g >> 5, h = g & 31;
    const int tid = threadIdx.x;
    const int r = tid >> 2, c = (tid & 3) * 16; // each thread: 1 row, 16 cols
    const ushort_t* src = qkv + ((size_t)(b * S_) + s0 + r) * (3 * H_ * D_) + h * (3 * D_) + 128 + c;
    *(short8*)&tile[r][c]     = *(const short8*)src;
    *(short8*)&tile[r][c + 8] = *(const short8*)(src + 8);
    __syncthreads();
    const int d = tid >> 2, cs = (tid & 3) * 16;
    ushort_t* dst = vt + ((size_t)g * D_ + d) * S_ + s0 + cs;
    short8 o0, o1;
#pragma unroll
    for (int j = 0; j < 8; j++) {
        o0[j] = (short)tile[cs + j][d];
        o1[j] = (short)tile[cs + 8 + j][d];
    }
    *(short8*)dst       = o0;
    *(short8*)(dst + 8) = o1;
}

// Flash attention: block-cooperative LDS staging of K/V tiles (global_load_lds,
// XOR-swizzled segs), transposed scores, fixed-reference softmax (exp2 domain,
// log2e folded into q), bitmask, cvt_pk P-pack.
__global__ __launch_bounds__(256) void attn_kernel(const ushort_t* __restrict__ qr,
                                                   const ushort_t* __restrict__ kr,
                                                   const ushort_t* __restrict__ vt,
                                                   const unsigned long long* __restrict__ mbits,
                                                   ushort_t* __restrict__ ctx) {
    __shared__ ushort_t lK[64 * 64];        // [k-local][d], segs XOR-swizzled by row&7
    __shared__ ushort_t lV[64 * 64];        // [d][k-local], same swizzle
    __shared__ ushort_t lds_p[4][16][72];   // per-wave P tile
    const int tid  = threadIdx.x;
    const int wave = tid >> 6, lane = tid & 63;
    const int quad = lane >> 4, l16 = lane & 15;

    const int id   = blockIdx.x;
    const int g    = (id & 7) | ((id >> 8) << 3);   // head-instance, 8 per XCD
    const int qblk = (id >> 3) & 31;
    const int b    = g >> 5;
    const int q0   = qblk * 64 + wave * 16;
    const size_t headBase = (size_t)g * S_ * D_;
    const unsigned long long* mrow = mbits + ((size_t)b * S_ + q0 + l16) * (S_ / 64);

    // staging: lane covers row sr (of 8), seg ss; global seg = ss ^ (row&7) = ss ^ sr
    const int sr = lane >> 3, ss = lane & 7;
    const int gss = ss ^ sr;
    const ushort_t* gK0 = kr + headBase + (size_t)(wave * 16 + sr) * D_ + gss * 8;
    const ushort_t* gV0 = vt + headBase + (size_t)(wave * 16 + sr) * S_ + gss * 8;

    // fragment read segs (element offsets): seg q ^ (row&7), row&7 = l16&7
    const int segA0 = ((quad)     ^ (l16 & 7)) * 8;
    const int segA1 = ((quad + 4) ^ (l16 & 7)) * 8;
    const int rowOff = (l16)*64;   // within 16-row group, * 64 elem/row

    // Q as B-operand (pre-scaled by log2e/8 at rope)
    short8 qf0 = *(const short8*)(qr + headBase + (size_t)(q0 + l16) * D_ + quad * 8);
    short8 qf1 = *(const short8*)(qr + headBase + (size_t)(q0 + l16) * D_ + 32 + quad * 8);

    float l_st = 0.f;
    floatx4 o[4];
#pragma unroll
    for (int t = 0; t < 4; t++) o[t] = (floatx4){0.f, 0.f, 0.f, 0.f};

    for (int k0 = 0; k0 < S_; k0 += 64) {
        // cooperative staging: 4 instrs/wave, 16/block, each 1 KB coalesced
#pragma unroll
        for (int i = 0; i < 2; i++) {
            __builtin_amdgcn_global_load_lds(
                (gas_ptr)(gK0 + (size_t)(k0 + i * 8) * D_),
                (las_ptr)(lK + (wave * 16 + i * 8) * 64), 16, 0, 0);
            __builtin_amdgcn_global_load_lds(
                (gas_ptr)(gV0 + (size_t)(i * 8) * S_ + k0),
                (las_ptr)(lV + (wave * 16 + i * 8) * 64), 16, 0, 0);
        }
        unsigned long long mb = mrow[k0 >> 6];
        __syncthreads();

        // QK^T transposed: scT rows = k-local, col = q (l16); K as A-operand from LDS
        floatx4 scT[4];
#pragma unroll
        for (int t = 0; t < 4; t++) scT[t] = (floatx4){0.f, 0.f, 0.f, 0.f};
#pragma unroll
        for (int t = 0; t < 4; t++) {
            short8 kf0 = *(const short8*)&lK[t * 1024 + rowOff + segA0];
            short8 kf1 = *(const short8*)&lK[t * 1024 + rowOff + segA1];
            scT[t] = __builtin_amdgcn_mfma_f32_16x16x32_bf16(kf0, qf0, scT[t], 0, 0, 0);
            scT[t] = __builtin_amdgcn_mfma_f32_16x16x32_bf16(kf1, qf1, scT[t], 0, 0, 0);
        }

        // fixed-reference softmax numerator (exp2 domain); masked -> 0
        unsigned mlo = (unsigned)(mb >> (quad * 4));
        unsigned mhi = (unsigned)(mb >> (quad * 4 + 32));
        float pv[4][4];
        float rs = 0.f;
#pragma unroll
        for (int t = 0; t < 4; t++) {
            unsigned msrc = (t < 2) ? mlo : mhi;
#pragma unroll
            for (int r = 0; r < 4; r++) {
                int bitpos = (t & 1) * 16 + r;
                float e = fexp2(scT[t][r]);
                e = ((msrc >> bitpos) & 1u) ? 0.f : e;
                pv[t][r] = e;
                rs += e;
            }
        }
        l_st += rs;

        // P row q=l16 -> per-wave LDS (C-layout -> A-layout), packed converts
#pragma unroll
        for (int t = 0; t < 4; t++) {
            uint2 w;
            w.x = cvt_pk_bf16(pv[t][0], pv[t][1]);
            w.y = cvt_pk_bf16(pv[t][2], pv[t][3]);
            *(uint2*)&lds_p[wave][l16][t * 16 + quad * 4] = w;
        }
        short8 pf0 = *(const short8*)&lds_p[wave][l16][quad * 8];
        short8 pf1 = *(const short8*)&lds_p[wave][l16][32 + quad * 8];

        // PV: V as B-operand from LDS
#pragma unroll
        for (int t = 0; t < 4; t++) {
            short8 vf0 = *(const short8*)&lV[t * 1024 + rowOff + segA0];
            short8 vf1 = *(const short8*)&lV[t * 1024 + rowOff + segA1];
            o[t] = __builtin_amdgcn_mfma_f32_16x16x32_bf16(pf0, vf0, o[t], 0, 0, 0);
            o[t] = __builtin_amdgcn_mfma_f32_16x16x32_bf16(pf1, vf1, o[t], 0, 0, 0);
        }
        __syncthreads();
    }

    // single end-of-kernel l reduction
    l_st += __shfl_xor(l_st, 16);
    l_st += __shfl_xor(l_st, 32);
    float li[4];
#pragma unroll
    for (int r = 0; r < 4; r++) li[r] = 1.0f / __shfl(l_st, quad * 4 + r, 16);
#pragma unroll
    for (int t = 0; t < 4; t++)
#pragma unroll
        for (int r = 0; r < 4; r++) {
            int srow = q0 + quad * 4 + r;
            ctx[((size_t)(b * S_) + srow) * (H_ * D_) + (g & 31) * D_ + t * 16 + l16] = f2bf(o[t][r] * li[r]);
        }
}

extern "C" void kernel_launch(void* const* d_in, const int* in_sizes, int n_in,
                              void* d_out, int out_size, void* d_ws, size_t ws_size,
                              hipStream_t stream) {
    const float* hidden          = (const float*)d_in[0];
    const int* mask              = (const int*)d_in[1];
    const int* pos               = (const int*)d_in[2];
    const float* Wqkv            = (const float*)d_in[3];
    const float* Wo              = (const float*)d_in[4];
    float* out                   = (float*)d_out;

    char* ws = (char*)d_ws;
    ushort_t* qkv     = (ushort_t*)(ws);
    ushort_t* ctx     = (ushort_t*)(ws);
    unsigned long long* mbits = (unsigned long long*)(ws + 16777216);
    ushort_t* Wo_bf   = (ushort_t*)(ws + 50331648);
    ushort_t* hid_bf  = (ushort_t*)(ws + 58720256);
    ushort_t* Wqkv_bf = (ushort_t*)(ws + 75497472);
    ushort_t* q_r     = (ushort_t*)(ws + 58720256);
    ushort_t* k_r     = (ushort_t*)(ws + 75497472);
    ushort_t* v_t     = (ushort_t*)(ws + 92274688);

    // 0. casts fp32 -> bf16
    {
        int n8 = (B_ * S_ * HID_) / 8;
        cast_f32_bf16<<<n8 / 256, 256, 0, stream>>>(hidden, hid_bf, n8);
        n8 = (3 * H_ * D_ * HID_) / 8;
        cast_f32_bf16<<<n8 / 256, 256, 0, stream>>>(Wqkv, Wqkv_bf, n8);
        n8 = (HID_ * H_ * D_) / 8;
        cast_f32_bf16<<<n8 / 256, 256, 0, stream>>>(Wo, Wo_bf, n8);
    }

    // 1. QKV projection
    gemm_bt<false><<<dim3((3 * H_ * D_) / 128, (B_ * S_) / 128), 256, 0, stream>>>(
        hid_bf, Wqkv_bf, qkv, B_ * S_, 3 * H_ * D_, HID_);

    // 2. RoPE (q,k) + v transpose (LDS-tiled)
    int nElem = B_ * H_ * S_ * D_;
    rope_qk<<<nElem / 256, 256, 0, stream>>>(qkv, pos, q_r, k_r);
    v_trans<<<B_ * H_ * (S_ / 64), 256, 0, stream>>>(qkv, v_t);

    // 2b. pack mask bits
    mask_pack<<<(B_ * S_ * S_) / 256, 256, 0, stream>>>(mask, mbits);

    // 3. Flash attention
    attn_kernel<<<2048, 256, 0, stream>>>(q_r, k_r, v_t, mbits, ctx);

    // 4. Output projection
    gemm_bt<true><<<dim3(HID_ / 128, (B_ * S_) / 128), 256, 0, stream>>>(
        ctx, Wo_bf, out, B_ * S_, HID_, H_ * D_);
}

// Round 2
// 358.060 us; speedup vs baseline: 1.2020x; 1.0067x over previous
//
#include <hip/hip_runtime.h>

#define B_   2
#define S_   2048
#define H_   32
#define D_   64
#define HID_ 2048

typedef unsigned short ushort_t;
typedef __attribute__((ext_vector_type(8))) short short8;
typedef __attribute__((ext_vector_type(4))) float floatx4;

typedef const __attribute__((address_space(1))) char* gas_ptr;
typedef __attribute__((address_space(3))) char* las_ptr;

__device__ __forceinline__ float bf2f(ushort_t u) {
    union { unsigned int i; float f; } v; v.i = ((unsigned int)u) << 16; return v.f;
}
__device__ __forceinline__ ushort_t f2bf(float f) {
    union { float f; unsigned int i; } v; v.f = f;
    unsigned int x = v.i;
    unsigned int r = x + 0x7fffu + ((x >> 16) & 1u);
    return (ushort_t)(r >> 16);
}

// exp2 via hardware v_exp_f32 (no log2e multiply).
__device__ __forceinline__ float fexp2(float x) {
#if __has_builtin(__builtin_amdgcn_exp2f)
    return __builtin_amdgcn_exp2f(x);
#else
    float r; asm("v_exp_f32 %0, %1" : "=v"(r) : "v"(x)); return r;
#endif
}

// Packed f32->bf16 RNE convert: dst = {lo16: cvt(a), hi16: cvt(b)}.
__device__ __forceinline__ unsigned cvt_pk_bf16(float a, float b) {
    unsigned r;
    asm("v_cvt_pk_bf16_f32 %0, %1, %2" : "=v"(r) : "v"(a), "v"(b));
    return r;
}

// fp32 -> bf16 cast, 8 elements/thread.
__global__ __launch_bounds__(256) void cast_f32_bf16(const float* __restrict__ in,
                                                     ushort_t* __restrict__ out,
                                                     int n8) {
    int i = blockIdx.x * 256 + threadIdx.x;
    if (i >= n8) return;
    const float4* p = (const float4*)(in + (size_t)i * 8);
    float4 a = p[0], b = p[1];
    uint4 o;
    o.x = cvt_pk_bf16(a.x, a.y);
    o.y = cvt_pk_bf16(a.z, a.w);
    o.z = cvt_pk_bf16(b.x, b.y);
    o.w = cvt_pk_bf16(b.z, b.w);
    *(uint4*)(out + (size_t)i * 8) = o;
}

// Pack int32 bool mask -> bitmask, 1 bit per element.
__global__ __launch_bounds__(256) void mask_pack(const int* __restrict__ m,
                                                 unsigned long long* __restrict__ bits) {
    int idx = blockIdx.x * 256 + threadIdx.x;
    unsigned long long bal = __ballot(m[idx] != 0);
    if ((threadIdx.x & 63) == 0) bits[idx >> 6] = bal;
}

// ---------------------------------------------------------------------------
// 256x256-tile, BK=64, 8-wave, 8-phase counted-vmcnt GEMM (C = A @ B^T, bf16 out).
// T2 (row&7 XOR seg swizzle) + T3/T4 (phase interleave, vmcnt(6)) + T5 (setprio)
// + T1 (XCD swizzle). LDS 128 KiB double-buffered, 1 block/CU.
// Stage units per K-tile: U0=A-first {rows 0-63,128-191}, U1=B-first {(r&63)<32},
// U2=B-second, U3=A-second. Each unit staged in a phase strictly after its last
// LDS read (barrier-separated -> deterministic WAR safety); read side guaranteed
// by boundary vmcnt(6) (3 units in flight) + barrier.
// ---------------------------------------------------------------------------
__global__ __launch_bounds__(512, 2) void gemm256_bt(const ushort_t* __restrict__ A,
                                                     const ushort_t* __restrict__ Bm,
                                                     ushort_t* __restrict__ C,
                                                     int M, int N, int K) {
    __shared__ ushort_t lA[2][256][64];
    __shared__ ushort_t lB[2][256][64];
    const int tid  = threadIdx.x;
    const int w    = tid >> 6, lane = tid & 63;
    const int quad = lane >> 4, l16 = lane & 15;
    const int wm = w >> 2, wn = w & 3;
    const int sr = lane >> 3, ss = lane & 7;
    const int gseg = (ss ^ sr) * 8;

    // T1: XCD-contiguous tile mapping (gridDim.x % 8 == 0)
    const int nbx = N >> 8;
    int id  = blockIdx.x;
    int cpx = gridDim.x >> 3;
    int swz = (id & 7) * cpx + (id >> 3);
    int by = swz / nbx, bx = swz - by * nbx;
    const int m0 = by * 256, n0 = bx * 256;

    // stage row bases (per wave), all ≡ 0 mod 8 so row&7 == sr
    int arow[2], brow[2];
    arow[0] = w * 8;                       arow[1] = 128 + w * 8;
    brow[0] = (w >> 2) * 64 + (w & 3) * 8; brow[1] = 128 + brow[0];

    const ushort_t *gAf[2], *gAs[2], *gBf[2], *gBs[2];
#pragma unroll
    for (int c = 0; c < 2; c++) {
        gAf[c] = A  + (size_t)(m0 + arow[c] + sr) * K + gseg;
        gAs[c] = A  + (size_t)(m0 + arow[c] + 64 + sr) * K + gseg;
        gBf[c] = Bm + (size_t)(n0 + brow[c] + sr) * K + gseg;
        gBs[c] = Bm + (size_t)(n0 + brow[c] + 32 + sr) * K + gseg;
    }

#define STAGE_AF(BUF, KT) do { _Pragma("unroll") for (int c = 0; c < 2; c++) \
    __builtin_amdgcn_global_load_lds((gas_ptr)(gAf[c] + (KT)), (las_ptr)&lA[BUF][arow[c]][0], 16, 0, 0); } while (0)
#define STAGE_AS(BUF, KT) do { _Pragma("unroll") for (int c = 0; c < 2; c++) \
    __builtin_amdgcn_global_load_lds((gas_ptr)(gAs[c] + (KT)), (las_ptr)&lA[BUF][arow[c] + 64][0], 16, 0, 0); } while (0)
#define STAGE_BF(BUF, KT) do { _Pragma("unroll") for (int c = 0; c < 2; c++) \
    __builtin_amdgcn_global_load_lds((gas_ptr)(gBf[c] + (KT)), (las_ptr)&lB[BUF][brow[c]][0], 16, 0, 0); } while (0)
#define STAGE_BS(BUF, KT) do { _Pragma("unroll") for (int c = 0; c < 2; c++) \
    __builtin_amdgcn_global_load_lds((gas_ptr)(gBs[c] + (KT)), (las_ptr)&lB[BUF][brow[c] + 32][0], 16, 0, 0); } while (0)

#define LDA_(Hh, BUF) do { _Pragma("unroll") for (int mi = 0; mi < 4; mi++) \
    _Pragma("unroll") for (int ks = 0; ks < 2; ks++) \
        aF[mi][ks] = *(const short8*)&lA[BUF][wm * 128 + (Hh) * 64 + mi * 16 + l16][(((ks * 4 + quad) ^ (l16 & 7)) * 8)]; } while (0)
#define LDB_(Gg, BUF) do { _Pragma("unroll") for (int ni = 0; ni < 2; ni++) \
    _Pragma("unroll") for (int ks = 0; ks < 2; ks++) \
        bF[Gg][ni][ks] = *(const short8*)&lB[BUF][wn * 64 + (Gg) * 32 + ni * 16 + l16][(((ks * 4 + quad) ^ (l16 & 7)) * 8)]; } while (0)

#define MM_(Hh, Gg) do { _Pragma("unroll") for (int mi = 0; mi < 4; mi++) \
    _Pragma("unroll") for (int ni = 0; ni < 2; ni++) \
    _Pragma("unroll") for (int ks = 0; ks < 2; ks++) \
        acc[(Hh) * 4 + mi][(Gg) * 2 + ni] = __builtin_amdgcn_mfma_f32_16x16x32_bf16( \
            aF[mi][ks], bF[Gg][ni][ks], acc[(Hh) * 4 + mi][(Gg) * 2 + ni], 0, 0, 0); } while (0)

    floatx4 acc[8][4];
#pragma unroll
    for (int i = 0; i < 8; i++)
#pragma unroll
        for (int j = 0; j < 4; j++) acc[i][j] = (floatx4){0.f, 0.f, 0.f, 0.f};
    short8 aF[4][2];
    short8 bF[2][2][2];

    const int NT = K >> 6;

    // prologue: tile0 complete (8 calls) + U0,U1,U2 of tile1 (6 calls)
    STAGE_AF(0, 0); STAGE_BF(0, 0); STAGE_BS(0, 0); STAGE_AS(0, 0);
    STAGE_AF(1, 64); STAGE_BF(1, 64); STAGE_BS(1, 64);
    asm volatile("s_waitcnt vmcnt(6)" ::: "memory");
    __builtin_amdgcn_s_barrier();

    for (int t = 0; t < NT; ++t) {
        const int buf = t & 1, nb = buf ^ 1;
        const int kt1 = (t + 1) << 6, kt2 = (t + 2) << 6;
        const bool g1 = (t + 1 < NT), g2 = (t + 2 < NT);

        // phase 0: read A-first + B-first; stage A-second(t+1)
        LDA_(0, buf); LDB_(0, buf);
        if (g1) STAGE_AS(nb, kt1);
        __builtin_amdgcn_s_barrier();
        __builtin_amdgcn_s_setprio(1);
        MM_(0, 0);
        __builtin_amdgcn_s_setprio(0);
        __builtin_amdgcn_s_barrier();

        // phase 1: read B-second; stage A-first(t+2)
        LDB_(1, buf);
        if (g2) STAGE_AF(buf, kt2);
        __builtin_amdgcn_s_barrier();
        __builtin_amdgcn_s_setprio(1);
        MM_(0, 1);
        __builtin_amdgcn_s_setprio(0);
        __builtin_amdgcn_s_barrier();

        // phase 2: read A-second; stage B-first(t+2)
        LDA_(1, buf);
        if (g2) STAGE_BF(buf, kt2);
        __builtin_amdgcn_s_barrier();
        __builtin_amdgcn_s_setprio(1);
        MM_(1, 1);
        __builtin_amdgcn_s_setprio(0);
        __builtin_amdgcn_s_barrier();

        // phase 3: stage B-second(t+2)
        if (g2) STAGE_BS(buf, kt2);
        __builtin_amdgcn_s_barrier();
        __builtin_amdgcn_s_setprio(1);
        MM_(1, 0);
        __builtin_amdgcn_s_setprio(0);

        // K-tile boundary: counted vmcnt (never 0 until final drain)
        if (t < NT - 2)       { asm volatile("s_waitcnt vmcnt(6)" ::: "memory"); }
        else if (t == NT - 2) { asm volatile("s_waitcnt vmcnt(0)" ::: "memory"); }
        __builtin_amdgcn_s_barrier();
    }

#pragma unroll
    for (int mi = 0; mi < 8; mi++)
#pragma unroll
        for (int ni = 0; ni < 4; ni++)
#pragma unroll
            for (int r = 0; r < 4; r++) {
                int row = m0 + wm * 128 + mi * 16 + quad * 4 + r;
                int col = n0 + wn * 64 + ni * 16 + l16;
                C[(size_t)row * N + col] = f2bf(acc[mi][ni][r]);
            }
#undef STAGE_AF
#undef STAGE_AS
#undef STAGE_BF
#undef STAGE_BS
#undef LDA_
#undef LDB_
#undef MM_
}

// C = A @ B^T.  (m97-style 128^2; kept for the 2048-wide output projection.)
template <bool OF32>
__global__ __launch_bounds__(256) void gemm_bt(const ushort_t* __restrict__ A,
                                               const ushort_t* __restrict__ Bm,
                                               void* __restrict__ Cv,
                                               int M, int N, int K) {
    __shared__ ushort_t lA[128 * 32];
    __shared__ ushort_t lB[128 * 32];
    const int tid  = threadIdx.x;
    const int lane = tid & 63, wave = tid >> 6;
    const int quad = lane >> 4, l16 = lane & 15;
    const int wm = wave >> 1, wn = wave & 1;
    const int m0 = blockIdx.y * 128, n0 = blockIdx.x * 128;

    const int srow = tid >> 2;
    const int gseg = (tid & 3) ^ ((tid >> 3) & 3);
    const ushort_t* gA = A + (size_t)(m0 + srow) * K + gseg * 8;
    const ushort_t* gB = Bm + (size_t)(n0 + srow) * K + gseg * 8;

    const int fseg = quad ^ ((l16 >> 1) & 3);

    floatx4 acc[4][4];
#pragma unroll
    for (int i = 0; i < 4; i++)
#pragma unroll
        for (int j = 0; j < 4; j++) acc[i][j] = (floatx4){0.f, 0.f, 0.f, 0.f};

    for (int k0 = 0; k0 < K; k0 += 32) {
#pragma unroll
        for (int j = 0; j < 2; j++) {
            __builtin_amdgcn_global_load_lds(
                (gas_ptr)(gA + (size_t)j * 64 * K + k0),
                (las_ptr)(lA + j * 2048 + wave * 512), 16, 0, 0);
            __builtin_amdgcn_global_load_lds(
                (gas_ptr)(gB + (size_t)j * 64 * K + k0),
                (las_ptr)(lB + j * 2048 + wave * 512), 16, 0, 0);
        }
        __syncthreads();

        short8 aF[4], bF[4];
#pragma unroll
        for (int mi = 0; mi < 4; mi++)
            aF[mi] = *(const short8*)&lA[(wm * 64 + mi * 16 + l16) * 32 + fseg * 8];
#pragma unroll
        for (int ni = 0; ni < 4; ni++)
            bF[ni] = *(const short8*)&lB[(wn * 64 + ni * 16 + l16) * 32 + fseg * 8];
#pragma unroll
        for (int mi = 0; mi < 4; mi++)
#pragma unroll
            for (int ni = 0; ni < 4; ni++)
                acc[mi][ni] = __builtin_amdgcn_mfma_f32_16x16x32_bf16(aF[mi], bF[ni], acc[mi][ni], 0, 0, 0);
        __syncthreads();
    }

#pragma unroll
    for (int mi = 0; mi < 4; mi++)
#pragma unroll
        for (int ni = 0; ni < 4; ni++)
#pragma unroll
            for (int r = 0; r < 4; r++) {
                int row = m0 + wm * 64 + mi * 16 + quad * 4 + r;
                int col = n0 + wn * 64 + ni * 16 + l16;
                if (OF32) ((float*)Cv)[(size_t)row * N + col] = acc[mi][ni][r];
                else      ((ushort_t*)Cv)[(size_t)row * N + col] = f2bf(acc[mi][ni][r]);
            }
}

// qkv: (B,S,H,3D) bf16 -> q_rot (pre-scaled by log2e/8), k_rot as (B,H,S,D) bf16.
__global__ __launch_bounds__(256) void rope_qk(const ushort_t* __restrict__ qkv,
                                               const int* __restrict__ pos,
                                               ushort_t* __restrict__ qr,
                                               ushort_t* __restrict__ kr) {
    int idx = blockIdx.x * 256 + threadIdx.x;   // (b,h,s,d): d fastest
    int d = idx & 63;
    int s = (idx >> 6) & 2047;
    int h = (idx >> 17) & 31;
    int b = idx >> 22;
    size_t qbase = ((size_t)(b * S_ + s)) * (3 * H_ * D_) + h * (3 * D_);
    int i  = d & 31;
    int d2 = d ^ 32;
    float x   = bf2f(qkv[qbase + d]);
    float xp  = bf2f(qkv[qbase + d2]);
    float kx  = bf2f(qkv[qbase + 64 + d]);
    float kxp = bf2f(qkv[qbase + 64 + d2]);
    int   p   = pos[b * S_ + s];
    // inv = 10000^(-2i/64) = exp2(-i * log2(10000)/32)
    float inv = fexp2((float)i * -0.41524101186092985f);
    float t   = (float)p * inv;
    float c = cosf(t), sn = sinf(t);
    float rq = (d < 32) ? -xp : xp;
    float rk = (d < 32) ? -kxp : kxp;
    // q pre-scale: (1/sqrt(64)) * log2(e) so attn can use raw exp2
    float qo = (x * c + rq * sn) * 0.18033688011112042f;
    float ko = kx * c + rk * sn;
    size_t o = ((size_t)(b * H_ + h) * S_ + s) * D_ + d;
    qr[o] = f2bf(qo);
    kr[o] = f2bf(ko);
}

// v transpose: qkv (B,S,H,3D) -> vt (B,H,D,S), LDS-tiled 64x64 (coalesced both sides).
__global__ __launch_bounds__(256) void v_trans(const ushort_t* __restrict__ qkv,
                                               ushort_t* __restrict__ vt) {
    __shared__ ushort_t tile[64][72];           // +8 pad
    const int bid = blockIdx.x;                 // grid = B*H * (S/64) = 2048
    const int g  = bid >> 5;                    // head-instance (b*H+h)
    const int s0 = (bid & 31) * 64;
    const int b = g >> 5, h = g & 31;
    const int tid = threadIdx.x;
    const int r = tid >> 2, c = (tid & 3) * 16; // each thread: 1 row, 16 cols
    const ushort_t* src = qkv + ((size_t)(b * S_) + s0 + r) * (3 * H_ * D_) + h * (3 * D_) + 128 + c;
    *(short8*)&tile[r][c]     = *(const short8*)src;
    *(short8*)&tile[r][c + 8] = *(const short8*)(src + 8);
    __syncthreads();
    const int d = tid >> 2, cs = (tid & 3) * 16;
    ushort_t* dst = vt + ((size_t)g * D_ + d) * S_ + s0 + cs;
    short8 o0, o1;
#pragma unroll
    for (int j = 0; j < 8; j++) {
        o0[j] = (short)tile[cs + j][d];
        o1[j] = (short)tile[cs + 8 + j][d];
    }
    *(short8*)dst       = o0;
    *(short8*)(dst + 8) = o1;
}

// Flash attention: block-cooperative LDS staging of K/V tiles (global_load_lds,
// XOR-swizzled segs), transposed scores, fixed-reference softmax (exp2 domain,
// log2e folded into q), bitmask, cvt_pk P-pack.
__global__ __launch_bounds__(256) void attn_kernel(const ushort_t* __restrict__ qr,
                                                   const ushort_t* __restrict__ kr,
                                                   const ushort_t* __restrict__ vt,
                                                   const unsigned long long* __restrict__ mbits,
                                                   ushort_t* __restrict__ ctx) {
    __shared__ ushort_t lK[64 * 64];        // [k-local][d], segs XOR-swizzled by row&7
    __shared__ ushort_t lV[64 * 64];        // [d][k-local], same swizzle
    __shared__ ushort_t lds_p[4][16][72];   // per-wave P tile
    const int tid  = threadIdx.x;
    const int wave = tid >> 6, lane = tid & 63;
    const int quad = lane >> 4, l16 = lane & 15;

    const int id   = blockIdx.x;
    const int g    = (id & 7) | ((id >> 8) << 3);   // head-instance, 8 per XCD
    const int qblk = (id >> 3) & 31;
    const int b    = g >> 5;
    const int q0   = qblk * 64 + wave * 16;
    const size_t headBase = (size_t)g * S_ * D_;
    const unsigned long long* mrow = mbits + ((size_t)b * S_ + q0 + l16) * (S_ / 64);

    // staging: lane covers row sr (of 8), seg ss; global seg = ss ^ (row&7) = ss ^ sr
    const int sr = lane >> 3, ss = lane & 7;
    const int gss = ss ^ sr;
    const ushort_t* gK0 = kr + headBase + (size_t)(wave * 16 + sr) * D_ + gss * 8;
    const ushort_t* gV0 = vt + headBase + (size_t)(wave * 16 + sr) * S_ + gss * 8;

    // fragment read segs (element offsets): seg q ^ (row&7), row&7 = l16&7
    const int segA0 = ((quad)     ^ (l16 & 7)) * 8;
    const int segA1 = ((quad + 4) ^ (l16 & 7)) * 8;
    const int rowOff = (l16)*64;   // within 16-row group, * 64 elem/row

    // Q as B-operand (pre-scaled by log2e/8 at rope)
    short8 qf0 = *(const short8*)(qr + headBase + (size_t)(q0 + l16) * D_ + quad * 8);
    short8 qf1 = *(const short8*)(qr + headBase + (size_t)(q0 + l16) * D_ + 32 + quad * 8);

    float l_st = 0.f;
    floatx4 o[4];
#pragma unroll
    for (int t = 0; t < 4; t++) o[t] = (floatx4){0.f, 0.f, 0.f, 0.f};

    for (int k0 = 0; k0 < S_; k0 += 64) {
        // cooperative staging: 4 instrs/wave, 16/block, each 1 KB coalesced
#pragma unroll
        for (int i = 0; i < 2; i++) {
            __builtin_amdgcn_global_load_lds(
                (gas_ptr)(gK0 + (size_t)(k0 + i * 8) * D_),
                (las_ptr)(lK + (wave * 16 + i * 8) * 64), 16, 0, 0);
            __builtin_amdgcn_global_load_lds(
                (gas_ptr)(gV0 + (size_t)(i * 8) * S_ + k0),
                (las_ptr)(lV + (wave * 16 + i * 8) * 64), 16, 0, 0);
        }
        unsigned long long mb = mrow[k0 >> 6];
        __syncthreads();

        // QK^T transposed: scT rows = k-local, col = q (l16); K as A-operand from LDS
        floatx4 scT[4];
#pragma unroll
        for (int t = 0; t < 4; t++) scT[t] = (floatx4){0.f, 0.f, 0.f, 0.f};
#pragma unroll
        for (int t = 0; t < 4; t++) {
            short8 kf0 = *(const short8*)&lK[t * 1024 + rowOff + segA0];
            short8 kf1 = *(const short8*)&lK[t * 1024 + rowOff + segA1];
            scT[t] = __builtin_amdgcn_mfma_f32_16x16x32_bf16(kf0, qf0, scT[t], 0, 0, 0);
            scT[t] = __builtin_amdgcn_mfma_f32_16x16x32_bf16(kf1, qf1, scT[t], 0, 0, 0);
        }

        // fixed-reference softmax numerator (exp2 domain); masked -> 0
        unsigned mlo = (unsigned)(mb >> (quad * 4));
        unsigned mhi = (unsigned)(mb >> (quad * 4 + 32));
        float pv[4][4];
        float rs = 0.f;
#pragma unroll
        for (int t = 0; t < 4; t++) {
            unsigned msrc = (t < 2) ? mlo : mhi;
#pragma unroll
            for (int r = 0; r < 4; r++) {
                int bitpos = (t & 1) * 16 + r;
                float e = fexp2(scT[t][r]);
                e = ((msrc >> bitpos) & 1u) ? 0.f : e;
                pv[t][r] = e;
                rs += e;
            }
        }
        l_st += rs;

        // P row q=l16 -> per-wave LDS (C-layout -> A-layout), packed converts
#pragma unroll
        for (int t = 0; t < 4; t++) {
            uint2 w;
            w.x = cvt_pk_bf16(pv[t][0], pv[t][1]);
            w.y = cvt_pk_bf16(pv[t][2], pv[t][3]);
            *(uint2*)&lds_p[wave][l16][t * 16 + quad * 4] = w;
        }
        short8 pf0 = *(const short8*)&lds_p[wave][l16][quad * 8];
        short8 pf1 = *(const short8*)&lds_p[wave][l16][32 + quad * 8];

        // PV: V as B-operand from LDS
#pragma unroll
        for (int t = 0; t < 4; t++) {
            short8 vf0 = *(const short8*)&lV[t * 1024 + rowOff + segA0];
            short8 vf1 = *(const short8*)&lV[t * 1024 + rowOff + segA1];
            o[t] = __builtin_amdgcn_mfma_f32_16x16x32_bf16(pf0, vf0, o[t], 0, 0, 0);
            o[t] = __builtin_amdgcn_mfma_f32_16x16x32_bf16(pf1, vf1, o[t], 0, 0, 0);
        }
        __syncthreads();
    }

    // single end-of-kernel l reduction
    l_st += __shfl_xor(l_st, 16);
    l_st += __shfl_xor(l_st, 32);
    float li[4];
#pragma unroll
    for (int r = 0; r < 4; r++) li[r] = 1.0f / __shfl(l_st, quad * 4 + r, 16);
#pragma unroll
    for (int t = 0; t < 4; t++)
#pragma unroll
        for (int r = 0; r < 4; r++) {
            int srow = q0 + quad * 4 + r;
            ctx[((size_t)(b * S_) + srow) * (H_ * D_) + (g & 31) * D_ + t * 16 + l16] = f2bf(o[t][r] * li[r]);
        }
}

extern "C" void kernel_launch(void* const* d_in, const int* in_sizes, int n_in,
                              void* d_out, int out_size, void* d_ws, size_t ws_size,
                              hipStream_t stream) {
    const float* hidden          = (const float*)d_in[0];
    const int* mask              = (const int*)d_in[1];
    const int* pos               = (const int*)d_in[2];
    const float* Wqkv            = (const float*)d_in[3];
    const float* Wo              = (const float*)d_in[4];
    float* out                   = (float*)d_out;

    char* ws = (char*)d_ws;
    ushort_t* qkv     = (ushort_t*)(ws);
    ushort_t* ctx     = (ushort_t*)(ws);
    unsigned long long* mbits = (unsigned long long*)(ws + 16777216);
    ushort_t* Wo_bf   = (ushort_t*)(ws + 50331648);
    ushort_t* hid_bf  = (ushort_t*)(ws + 58720256);
    ushort_t* Wqkv_bf = (ushort_t*)(ws + 75497472);
    ushort_t* q_r     = (ushort_t*)(ws + 58720256);
    ushort_t* k_r     = (ushort_t*)(ws + 75497472);
    ushort_t* v_t     = (ushort_t*)(ws + 92274688);

    // 0. casts fp32 -> bf16
    {
        int n8 = (B_ * S_ * HID_) / 8;
        cast_f32_bf16<<<n8 / 256, 256, 0, stream>>>(hidden, hid_bf, n8);
        n8 = (3 * H_ * D_ * HID_) / 8;
        cast_f32_bf16<<<n8 / 256, 256, 0, stream>>>(Wqkv, Wqkv_bf, n8);
        n8 = (HID_ * H_ * D_) / 8;
        cast_f32_bf16<<<n8 / 256, 256, 0, stream>>>(Wo, Wo_bf, n8);
    }

    // 1. QKV projection: 256^2 8-phase counted-vmcnt GEMM (384 blocks)
    gemm256_bt<<<((3 * H_ * D_) / 256) * ((B_ * S_) / 256), 512, 0, stream>>>(
        hid_bf, Wqkv_bf, qkv, B_ * S_, 3 * H_ * D_, HID_);

    // 2. RoPE (q,k) + v transpose (LDS-tiled)
    int nElem = B_ * H_ * S_ * D_;
    rope_qk<<<nElem / 256, 256, 0, stream>>>(qkv, pos, q_r, k_r);
    v_trans<<<B_ * H_ * (S_ / 64), 256, 0, stream>>>(qkv, v_t);

    // 2b. pack mask bits
    mask_pack<<<(B_ * S_ * S_) / 256, 256, 0, stream>>>(mask, mbits);

    // 3. Flash attention
    attn_kernel<<<2048, 256, 0, stream>>>(q_r, k_r, v_t, mbits, ctx);

    // 4. Output projection (128^2: N=2048 -> 256 blocks fills the machine better)
    gemm_bt<true><<<dim3(HID_ / 128, (B_ * S_) / 128), 256, 0, stream>>>(
        ctx, Wo_bf, out, B_ * S_, HID_, H_ * D_);
}